// Round 1
// baseline (62.764 us; speedup 1.0000x reference)
//
#include <hip/hip_runtime.h>

// Fused NeRF: positional encoding (4 freq bands) + MLP 27->32->1 with ReLU.
// One thread per point. Weights via wave-uniform s_load; x staged via LDS.

#define NPTS 2097152
#define BLOCK 256

// sin/cos with explicit reduction to revolutions: sin(x) = v_sin(fract(x/2pi)).
// |x| <= ~5600 rad -> fp32 reduction error <= ~4e-4 rad, fine vs 5.2e-2 tol.
__device__ __forceinline__ void fast_sincos(float xr, float& s, float& c) {
    float r = xr * 0.15915494309189535f;  // revolutions
    float fr = r - floorf(r);             // [0,1) -> v_fract
    s = __builtin_amdgcn_sinf(fr);        // v_sin_f32: D = sin(S0 * 2pi)
    c = __builtin_amdgcn_cosf(fr);        // v_cos_f32
}

__global__ __launch_bounds__(BLOCK) void nerf_fused(
    const float* __restrict__ x,
    const float* __restrict__ W1,
    const float* __restrict__ b1,
    const float* __restrict__ W2,
    const float* __restrict__ b2,
    float* __restrict__ out)
{
    __shared__ float sx[BLOCK * 3];
    const int tid = threadIdx.x;
    const long long base = (long long)blockIdx.x * BLOCK;

    // Coalesced stage of this block's 256 points (768 floats) into LDS.
    const float* xb = x + base * 3;
    #pragma unroll
    for (int k = 0; k < 3; ++k) sx[tid + k * BLOCK] = xb[tid + k * BLOCK];
    __syncthreads();

    // stride-3 LDS read: gcd(3,32)=1 -> conflict-free
    const float x0 = sx[tid * 3 + 0];
    const float x1 = sx[tid * 3 + 1];
    const float x2 = sx[tid * 3 + 2];

    // FREQ_BANDS = 2^linspace(0,10,4) (fp32)
    const float F[4] = {1.0f, 10.0793684f, 101.5936673f, 1024.0f};

    // t = [x, sin(f0*x)(3), cos(f0*x)(3), sin(f1*x)(3), cos(f1*x)(3), ...] : 27
    float t[27];
    t[0] = x0; t[1] = x1; t[2] = x2;
    #pragma unroll
    for (int f = 0; f < 4; ++f) {
        fast_sincos(x0 * F[f], t[3 + 6 * f + 0], t[3 + 6 * f + 3]);
        fast_sincos(x1 * F[f], t[3 + 6 * f + 1], t[3 + 6 * f + 4]);
        fast_sincos(x2 * F[f], t[3 + 6 * f + 2], t[3 + 6 * f + 5]);
    }

    // Layer 1: h = relu(t @ W1 + b1). i-major so every weight access is a
    // wave-uniform constant offset -> scalar loads; FMA = v_fmac(v, s, v).
    float h[32];
    #pragma unroll
    for (int j = 0; j < 32; ++j) h[j] = b1[j];
    #pragma unroll
    for (int i = 0; i < 27; ++i) {
        const float ti = t[i];
        #pragma unroll
        for (int j = 0; j < 32; ++j) h[j] = fmaf(ti, W1[i * 32 + j], h[j]);
    }

    // Layer 2: out = relu(relu(h) @ W2 + b2)
    float o = b2[0];
    #pragma unroll
    for (int j = 0; j < 32; ++j) o = fmaf(fmaxf(h[j], 0.0f), W2[j], o);

    out[base + tid] = fmaxf(o, 0.0f);
}

extern "C" void kernel_launch(void* const* d_in, const int* in_sizes, int n_in,
                              void* d_out, int out_size, void* d_ws, size_t ws_size,
                              hipStream_t stream) {
    const float* x  = (const float*)d_in[0];
    const float* W1 = (const float*)d_in[1];
    const float* b1 = (const float*)d_in[2];
    const float* W2 = (const float*)d_in[3];
    const float* b2 = (const float*)d_in[4];
    float* out = (float*)d_out;

    const int nblocks = NPTS / BLOCK;  // 2097152 / 256 = 8192
    nerf_fused<<<nblocks, BLOCK, 0, stream>>>(x, W1, b1, W2, b2, out);
}

// Round 2
// 30.101 us; speedup vs baseline: 2.0851x; 2.0851x over previous
//
#include <hip/hip_runtime.h>

// Fused NeRF: PE (4 freq bands) + MLP 27->32->1 via bf16 MFMA (swapped operands).
// Layer 1: D[j][point] = mfma(A = W1^T (+bias row at k=27), B = t^T).
// C layout (verified m89): col = lane&15 (point), row = (lane>>4)*4 + reg (j).
// Layer 2: per-lane 8 FMAs over its j-slice, then xor16/xor32 reduce.

#define NPTS 2097152
#define TROW 40   // LDS row stride in bf16 elems (80 B): 16B-aligned, bank-friendly

typedef __bf16 bf16x8 __attribute__((ext_vector_type(8)));
typedef float  f32x4  __attribute__((ext_vector_type(4)));

__global__ __launch_bounds__(256) void nerf_mfma(
    const float* __restrict__ x,
    const float* __restrict__ W1,
    const float* __restrict__ b1,
    const float* __restrict__ W2,
    const float* __restrict__ b2,
    float* __restrict__ out)
{
    __shared__ __bf16 tbuf[4][64 * TROW];  // per-wave 64 rows x 40 bf16 = 5 KB
    __shared__ float  sx[4][192];

    const int tid  = threadIdx.x;
    const int wave = tid >> 6;
    const int lane = tid & 63;
    const int g    = lane >> 4;   // k-group / row-group
    const int c    = lane & 15;   // col-within-16

    const long long waveBase = (long long)blockIdx.x * 256 + wave * 64;

    // ---- A-fragments: Ahat[j][k] = k<27 ? W1[k*32+j] : (k==27 ? b1[j] : 0)
    // assumed A layout: m = lane&15 (j within mtile), k = g*8 + i (K-chunk per lane)
    bf16x8 afrag[2];
    #pragma unroll
    for (int mt = 0; mt < 2; ++mt) {
        const int j = mt * 16 + c;
        #pragma unroll
        for (int i = 0; i < 8; ++i) {
            const int k = g * 8 + i;
            float v = 0.0f;
            if (k < 27)       v = W1[k * 32 + j];
            else if (k == 27) v = b1[j];
            afrag[mt][i] = (__bf16)v;
        }
    }
    // per-lane W2 slice: layer-2 j = mt*16 + g*4 + r  (C-layout rows this lane owns)
    float w2v[2][4];
    #pragma unroll
    for (int mt = 0; mt < 2; ++mt)
        #pragma unroll
        for (int r = 0; r < 4; ++r)
            w2v[mt][r] = W2[mt * 16 + g * 4 + r];
    const float bias2 = b2[0];

    // ---- stage x coalesced into LDS, read back per-point (stride-3: conflict-free)
    const float* xw = x + waveBase * 3;
    #pragma unroll
    for (int q = 0; q < 3; ++q) sx[wave][lane + q * 64] = xw[lane + q * 64];
    asm volatile("s_waitcnt lgkmcnt(0)" ::: "memory");
    const float x0 = sx[wave][lane * 3 + 0];
    const float x1 = sx[wave][lane * 3 + 1];
    const float x2 = sx[wave][lane * 3 + 2];

    // ---- positional encoding in revolutions (freq premultiplied by 1/2pi)
    const float Fr[4] = {
        0.15915494309189535f,
        10.079368f  * 0.15915494309189535f,
        101.59367f  * 0.15915494309189535f,
        1024.0f     * 0.15915494309189535f
    };
    bf16x8 tch[4] = {};  // 32 bf16 feature slots; pads stay 0
#define TSET(idx, val) tch[(idx) / 8][(idx) % 8] = (__bf16)(val)
    TSET(0, x0); TSET(1, x1); TSET(2, x2);
    #pragma unroll
    for (int f = 0; f < 4; ++f) {
        const float r0 = x0 * Fr[f], r1 = x1 * Fr[f], r2 = x2 * Fr[f];
        const float a0 = r0 - floorf(r0);
        const float a1 = r1 - floorf(r1);
        const float a2 = r2 - floorf(r2);
        TSET(3 + 6 * f + 0, __builtin_amdgcn_sinf(a0));
        TSET(3 + 6 * f + 1, __builtin_amdgcn_sinf(a1));
        TSET(3 + 6 * f + 2, __builtin_amdgcn_sinf(a2));
        TSET(3 + 6 * f + 3, __builtin_amdgcn_cosf(a0));
        TSET(3 + 6 * f + 4, __builtin_amdgcn_cosf(a1));
        TSET(3 + 6 * f + 5, __builtin_amdgcn_cosf(a2));
    }
    TSET(27, 1.0f);  // bias row multiplier
#undef TSET

    // ---- write my t-row (64 B as 4x ds_write_b128), rows are wave-local
    __bf16* myrow = &tbuf[wave][lane * TROW];
    #pragma unroll
    for (int ch = 0; ch < 4; ++ch)
        *(bf16x8*)(myrow + ch * 8) = tch[ch];

    asm volatile("s_waitcnt lgkmcnt(0)" ::: "memory");

    // ---- B-fragments: lane reads point row = nt*16 + c, K-chunk g*8..+7
    bf16x8 bfrag[4];
    #pragma unroll
    for (int nt = 0; nt < 4; ++nt)
        bfrag[nt] = *(bf16x8*)(&tbuf[wave][(nt * 16 + c) * TROW + g * 8]);

    // ---- layer 1: 8 MFMAs, D[j][point]
    f32x4 acc[4][2] = {};
    #pragma unroll
    for (int nt = 0; nt < 4; ++nt)
        #pragma unroll
        for (int mt = 0; mt < 2; ++mt)
            acc[nt][mt] = __builtin_amdgcn_mfma_f32_16x16x32_bf16(
                afrag[mt], bfrag[nt], acc[nt][mt], 0, 0, 0);

    // ---- layer 2: per-lane partial over its 8 j's, reduce across groups
    float sum[4];
    #pragma unroll
    for (int nt = 0; nt < 4; ++nt) {
        float s = 0.0f;
        #pragma unroll
        for (int mt = 0; mt < 2; ++mt)
            #pragma unroll
            for (int r = 0; r < 4; ++r)
                s = fmaf(fmaxf(acc[nt][mt][r], 0.0f), w2v[mt][r], s);
        s += __shfl_xor(s, 16, 64);
        s += __shfl_xor(s, 32, 64);
        sum[nt] = s;
    }

    // lane writes point c + 16*g  ->  select sum[g] (static-index cndmask chain)
    float v = sum[0];
    v = (g == 1) ? sum[1] : v;
    v = (g == 2) ? sum[2] : v;
    v = (g == 3) ? sum[3] : v;
    out[waveBase + lane] = fmaxf(v + bias2, 0.0f);
}

extern "C" void kernel_launch(void* const* d_in, const int* in_sizes, int n_in,
                              void* d_out, int out_size, void* d_ws, size_t ws_size,
                              hipStream_t stream) {
    const float* x  = (const float*)d_in[0];
    const float* W1 = (const float*)d_in[1];
    const float* b1 = (const float*)d_in[2];
    const float* W2 = (const float*)d_in[3];
    const float* b2 = (const float*)d_in[4];
    float* out = (float*)d_out;

    nerf_mfma<<<NPTS / 256, 256, 0, stream>>>(x, W1, b1, W2, b2, out);
}

// Round 3
// 23.638 us; speedup vs baseline: 2.6552x; 1.2734x over previous
//
#include <hip/hip_runtime.h>

// Fused NeRF: PE (4 freq bands) + MLP 27->32->1 via bf16 MFMA (swapped operands).
// Tiled-persistent: 1024 blocks, each wave loops over 8 tiles of 64 points.
// Weights hoisted; next tile's x prefetched during current tile's compute.

#define NPTS  2097152
#define BLOCK 256
#define TILES 8
#define NBLK  (NPTS / (BLOCK * TILES))   // 1024
#define TROW  40   // LDS row stride in bf16 (80 B): 16B-aligned, bank-friendly

typedef __bf16 bf16x8 __attribute__((ext_vector_type(8)));
typedef float  f32x4  __attribute__((ext_vector_type(4)));
typedef float  f32x2  __attribute__((ext_vector_type(2)));

__global__ __launch_bounds__(BLOCK) void nerf_mfma2(
    const float* __restrict__ x,
    const float* __restrict__ W1,
    const float* __restrict__ b1,
    const float* __restrict__ W2,
    const float* __restrict__ b2,
    float* __restrict__ out)
{
    __shared__ __bf16 tbuf[4][64 * TROW];  // per-wave private 5 KB

    const int tid  = threadIdx.x;
    const int wave = tid >> 6;
    const int lane = tid & 63;
    const int g    = lane >> 4;   // K-chunk / row-group
    const int c    = lane & 15;   // col-within-16

    // ---- weights once per thread (amortized over 8 tiles) ----
    // Ahat[j][k] = k<27 ? W1[k*32+j] : (k==27 ? b1[j] : 0); m=c, k=g*8+i
    bf16x8 afrag[2];
    #pragma unroll
    for (int mt = 0; mt < 2; ++mt) {
        const int j = mt * 16 + c;
        #pragma unroll
        for (int i = 0; i < 8; ++i) {
            const int k = g * 8 + i;
            float v = 0.0f;
            if (k < 27)       v = W1[k * 32 + j];
            else if (k == 27) v = b1[j];
            afrag[mt][i] = (__bf16)v;
        }
    }
    // layer-2 weights for the j-rows this lane owns: j = mt*16 + g*4 + r
    f32x2 w2p[2][2];
    #pragma unroll
    for (int mt = 0; mt < 2; ++mt)
        #pragma unroll
        for (int rr = 0; rr < 2; ++rr) {
            w2p[mt][rr][0] = W2[mt * 16 + g * 4 + 2 * rr + 0];
            w2p[mt][rr][1] = W2[mt * 16 + g * 4 + 2 * rr + 1];
        }
    const float bias2 = b2[0];

    const float Fr[4] = {
        0.15915494309189535f,
        10.079368f * 0.15915494309189535f,
        101.59367f * 0.15915494309189535f,
        1024.0f    * 0.15915494309189535f
    };

    // wave's 8 consecutive tiles
    const int tbase = blockIdx.x * (4 * TILES) + wave * TILES;

    // prefetch tile 0's x (per-lane, 768 contiguous B per wave per component set)
    int p0 = (tbase + 0) * 64 + lane;
    float nx0 = x[p0 * 3 + 0], nx1 = x[p0 * 3 + 1], nx2 = x[p0 * 3 + 2];

    #pragma unroll
    for (int t = 0; t < TILES; ++t) {
        const float x0 = nx0, x1 = nx1, x2 = nx2;
        if (t + 1 < TILES) {  // issue next tile's loads early; hides under compute
            const int pn = (tbase + t + 1) * 64 + lane;
            nx0 = x[pn * 3 + 0]; nx1 = x[pn * 3 + 1]; nx2 = x[pn * 3 + 2];
        }

        // ---- positional encoding (revolutions reduction; v_sin/v_cos) ----
        bf16x8 tch[4] = {};
#define TSET(idx, val) tch[(idx) / 8][(idx) % 8] = (__bf16)(val)
        TSET(0, x0); TSET(1, x1); TSET(2, x2);
        #pragma unroll
        for (int f = 0; f < 4; ++f) {
            const float r0 = x0 * Fr[f], r1 = x1 * Fr[f], r2 = x2 * Fr[f];
            const float a0 = r0 - floorf(r0);
            const float a1 = r1 - floorf(r1);
            const float a2 = r2 - floorf(r2);
            TSET(3 + 6 * f + 0, __builtin_amdgcn_sinf(a0));
            TSET(3 + 6 * f + 1, __builtin_amdgcn_sinf(a1));
            TSET(3 + 6 * f + 2, __builtin_amdgcn_sinf(a2));
            TSET(3 + 6 * f + 3, __builtin_amdgcn_cosf(a0));
            TSET(3 + 6 * f + 4, __builtin_amdgcn_cosf(a1));
            TSET(3 + 6 * f + 5, __builtin_amdgcn_cosf(a2));
        }
        TSET(27, 1.0f);  // bias row
#undef TSET

        // ---- t-row -> LDS (wave-private; same-wave DS ops are in-order) ----
        __bf16* myrow = &tbuf[wave][lane * TROW];
        #pragma unroll
        for (int ch = 0; ch < 4; ++ch)
            *(bf16x8*)(myrow + ch * 8) = tch[ch];

        asm volatile("s_waitcnt lgkmcnt(0)" ::: "memory");

        // B-fragment: point row nt*16 + c, K-chunk g*8..+7
        bf16x8 bfrag[4];
        #pragma unroll
        for (int nt = 0; nt < 4; ++nt)
            bfrag[nt] = *(bf16x8*)(&tbuf[wave][(nt * 16 + c) * TROW + g * 8]);

        // ---- layer 1: 8 MFMAs ----
        f32x4 acc[4][2] = {};
        #pragma unroll
        for (int nt = 0; nt < 4; ++nt)
            #pragma unroll
            for (int mt = 0; mt < 2; ++mt)
                acc[nt][mt] = __builtin_amdgcn_mfma_f32_16x16x32_bf16(
                    afrag[mt], bfrag[nt], acc[nt][mt], 0, 0, 0);

        // ---- layer 2: packed relu+fma over lane's 8 j's, xor16/xor32 reduce ----
        float sum[4];
        #pragma unroll
        for (int nt = 0; nt < 4; ++nt) {
            f32x2 ps = {0.0f, 0.0f};
            #pragma unroll
            for (int mt = 0; mt < 2; ++mt) {
                #pragma unroll
                for (int rr = 0; rr < 2; ++rr) {
                    f32x2 a;
                    a[0] = fmaxf(acc[nt][mt][2 * rr + 0], 0.0f);
                    a[1] = fmaxf(acc[nt][mt][2 * rr + 1], 0.0f);
                    ps = ps + a * w2p[mt][rr];   // v_pk_fma_f32 candidate
                }
            }
            float s = ps[0] + ps[1];
            s += __shfl_xor(s, 16, 64);
            s += __shfl_xor(s, 32, 64);
            sum[nt] = s;
        }

        // lane's point is col c of n-tile g -> pick sum[g]
        float v = sum[0];
        v = (g == 1) ? sum[1] : v;
        v = (g == 2) ? sum[2] : v;
        v = (g == 3) ? sum[3] : v;
        out[(tbase + t) * 64 + lane] = fmaxf(v + bias2, 0.0f);
    }
}

extern "C" void kernel_launch(void* const* d_in, const int* in_sizes, int n_in,
                              void* d_out, int out_size, void* d_ws, size_t ws_size,
                              hipStream_t stream) {
    const float* x  = (const float*)d_in[0];
    const float* W1 = (const float*)d_in[1];
    const float* b1 = (const float*)d_in[2];
    const float* W2 = (const float*)d_in[3];
    const float* b2 = (const float*)d_in[4];
    float* out = (float*)d_out;

    nerf_mfma2<<<NBLK, BLOCK, 0, stream>>>(x, W1, b1, W2, b2, out);
}

// Round 4
// 21.315 us; speedup vs baseline: 2.9445x; 1.1090x over previous
//
#include <hip/hip_runtime.h>

// Fused NeRF: PE (4 freq) + MLP 27->32->1 via bf16 MFMA (swapped operands).
// 2048 blocks x 4 tiles/wave. No inline-asm barriers: wave-private LDS is
// in-order per wave; compiler inserts lgkmcnt waits and can pipeline tiles.

#define NPTS  2097152
#define BLOCK 256
#define TILES 4
#define NBLK  (NPTS / (BLOCK * TILES))   // 2048
#define TROW  40   // LDS row stride in bf16 (80 B), 16B-aligned

typedef __bf16 bf16x8 __attribute__((ext_vector_type(8)));
typedef float  f32x4  __attribute__((ext_vector_type(4)));
typedef float  f32x2  __attribute__((ext_vector_type(2)));

__global__ __launch_bounds__(BLOCK, 4) void nerf_mfma3(
    const float* __restrict__ x,
    const float* __restrict__ W1,
    const float* __restrict__ b1,
    const float* __restrict__ W2,
    const float* __restrict__ b2,
    float* __restrict__ out)
{
    __shared__ __bf16 tbuf[4][64 * TROW];  // per-wave private 5 KB

    const int tid  = threadIdx.x;
    const int wave = tid >> 6;
    const int lane = tid & 63;
    const int g    = lane >> 4;   // K-chunk / j-row group
    const int c    = lane & 15;   // col-within-16

    // ---- hoisted weights ----
    // Ahat[j][k] = k<27 ? W1[k*32+j] : (k==27 ? b1[j] : 0); m=c, k=g*8+i
    bf16x8 afrag[2];
    #pragma unroll
    for (int mt = 0; mt < 2; ++mt) {
        const int j = mt * 16 + c;
        #pragma unroll
        for (int i = 0; i < 8; ++i) {
            const int k = g * 8 + i;
            float v = 0.0f;
            if (k < 27)       v = W1[k * 32 + j];
            else if (k == 27) v = b1[j];
            afrag[mt][i] = (__bf16)v;
        }
    }
    // layer-2 weights for lane's j rows: j = mt*16 + g*4 + r
    f32x2 w2p[2][2];
    #pragma unroll
    for (int mt = 0; mt < 2; ++mt)
        #pragma unroll
        for (int rr = 0; rr < 2; ++rr) {
            w2p[mt][rr][0] = W2[mt * 16 + g * 4 + 2 * rr + 0];
            w2p[mt][rr][1] = W2[mt * 16 + g * 4 + 2 * rr + 1];
        }
    const float bias2 = b2[0];

    const float Fr[4] = {
        0.15915494309189535f,
        10.079368f * 0.15915494309189535f,
        101.59367f * 0.15915494309189535f,
        1024.0f    * 0.15915494309189535f
    };

    const int tbase = blockIdx.x * (4 * TILES) + wave * TILES;

    float nx0, nx1, nx2;
    {
        const int p0 = tbase * 64 + lane;
        nx0 = x[p0 * 3 + 0]; nx1 = x[p0 * 3 + 1]; nx2 = x[p0 * 3 + 2];
    }

    #pragma unroll
    for (int t = 0; t < TILES; ++t) {
        const float x0 = nx0, x1 = nx1, x2 = nx2;
        if (t + 1 < TILES) {  // prefetch next tile's x; hides under compute
            const int pn = (tbase + t + 1) * 64 + lane;
            nx0 = x[pn * 3 + 0]; nx1 = x[pn * 3 + 1]; nx2 = x[pn * 3 + 2];
        }

        // ---- positional encoding (revolutions; v_sin/v_cos) ----
        bf16x8 tch[4] = {};
#define TSET(idx, val) tch[(idx) / 8][(idx) % 8] = (__bf16)(val)
        TSET(0, x0); TSET(1, x1); TSET(2, x2);
        #pragma unroll
        for (int f = 0; f < 4; ++f) {
            const float r0 = x0 * Fr[f], r1 = x1 * Fr[f], r2 = x2 * Fr[f];
            const float a0 = r0 - floorf(r0);
            const float a1 = r1 - floorf(r1);
            const float a2 = r2 - floorf(r2);
            TSET(3 + 6 * f + 0, __builtin_amdgcn_sinf(a0));
            TSET(3 + 6 * f + 1, __builtin_amdgcn_sinf(a1));
            TSET(3 + 6 * f + 2, __builtin_amdgcn_sinf(a2));
            TSET(3 + 6 * f + 3, __builtin_amdgcn_cosf(a0));
            TSET(3 + 6 * f + 4, __builtin_amdgcn_cosf(a1));
            TSET(3 + 6 * f + 5, __builtin_amdgcn_cosf(a2));
        }
        TSET(27, 1.0f);  // bias row multiplier
#undef TSET

        // ---- transpose via wave-private LDS (in-order DS; no barrier) ----
        __bf16* myrow = &tbuf[wave][lane * TROW];
        #pragma unroll
        for (int ch = 0; ch < 4; ++ch)
            *(bf16x8*)(myrow + ch * 8) = tch[ch];

        bf16x8 bfrag[4];
        #pragma unroll
        for (int nt = 0; nt < 4; ++nt)
            bfrag[nt] = *(bf16x8*)(&tbuf[wave][(nt * 16 + c) * TROW + g * 8]);

        // ---- layer 1: 8 MFMAs; D[j][point] ----
        f32x4 acc[4][2] = {};
        #pragma unroll
        for (int nt = 0; nt < 4; ++nt)
            #pragma unroll
            for (int mt = 0; mt < 2; ++mt)
                acc[nt][mt] = __builtin_amdgcn_mfma_f32_16x16x32_bf16(
                    afrag[mt], bfrag[nt], acc[nt][mt], 0, 0, 0);

        // ---- layer 2: per-lane partials over its 8 j's ----
        float p[4];
        #pragma unroll
        for (int nt = 0; nt < 4; ++nt) {
            f32x2 ps = {0.0f, 0.0f};
            #pragma unroll
            for (int mt = 0; mt < 2; ++mt)
                #pragma unroll
                for (int rr = 0; rr < 2; ++rr) {
                    f32x2 a;
                    a[0] = fmaxf(acc[nt][mt][2 * rr + 0], 0.0f);
                    a[1] = fmaxf(acc[nt][mt][2 * rr + 1], 0.0f);
                    ps = ps + a * w2p[mt][rr];
                }
            p[nt] = ps[0] + ps[1];
        }

        // ---- select-exchange butterfly: lane ends with its own point's sum
        // stage A (xor32, partner g^2): exchange the nt-pair the partner owns
        const bool hi2 = (g >= 2), odd = (g & 1);
        const float s0 = hi2 ? p[0] : p[2];
        const float s1 = hi2 ? p[1] : p[3];
        const float k0 = hi2 ? p[2] : p[0];
        const float k1 = hi2 ? p[3] : p[1];
        const float r0 = k0 + __shfl_xor(s0, 32, 64);   // nt = 2*(g>>1)
        const float r1 = k1 + __shfl_xor(s1, 32, 64);   // nt = 2*(g>>1)+1
        // stage B (xor16, partner g^1)
        const float uk = odd ? r1 : r0;
        const float us = odd ? r0 : r1;
        const float S  = uk + __shfl_xor(us, 16, 64);   // nt = g

        out[(tbase + t) * 64 + lane] = fmaxf(S + bias2, 0.0f);
    }
}

extern "C" void kernel_launch(void* const* d_in, const int* in_sizes, int n_in,
                              void* d_out, int out_size, void* d_ws, size_t ws_size,
                              hipStream_t stream) {
    const float* x  = (const float*)d_in[0];
    const float* W1 = (const float*)d_in[1];
    const float* b1 = (const float*)d_in[2];
    const float* W2 = (const float*)d_in[3];
    const float* b2 = (const float*)d_in[4];
    float* out = (float*)d_out;

    nerf_mfma3<<<NBLK, BLOCK, 0, stream>>>(x, W1, b1, W2, b2, out);
}

// Round 5
// 20.093 us; speedup vs baseline: 3.1237x; 1.0608x over previous
//
#include <hip/hip_runtime.h>

// Fused NeRF: PE (4 freq) + MLP 27->32->1 via bf16 MFMA, swapped operands.
// K-axis REORDERED so each lane's B-fragment is computed locally (no LDS):
//   k = 8*g + s, slots = [sin_g(x0),sin_g(x1),sin_g(x2),
//                         cos_g(x0),cos_g(x1),cos_g(x2), extra_g, 0]
//   extra_g = x0|x1|x2|1.0 for g=0..3 (bias folded at g=3).
// W1 rows permuted to match inside the hoisted afrag gather.

#define NPTS  2097152
#define BLOCK 256
#define TILES 4
#define NBLK  (NPTS / (BLOCK * TILES))   // 2048

typedef __bf16 bf16x8 __attribute__((ext_vector_type(8)));
typedef float  f32x4  __attribute__((ext_vector_type(4)));
typedef float  f32x2  __attribute__((ext_vector_type(2)));

__global__ __launch_bounds__(BLOCK, 4) void nerf_mfma4(
    const float* __restrict__ x,
    const float* __restrict__ W1,
    const float* __restrict__ b1,
    const float* __restrict__ W2,
    const float* __restrict__ b2,
    float* __restrict__ out)
{
    const int tid  = threadIdx.x;
    const int wave = tid >> 6;
    const int lane = tid & 63;
    const int g    = lane >> 4;   // K-group: this lane's frequency band
    const int c    = lane & 15;   // col-within-16 (point index low bits)

    // per-lane frequency, premultiplied by 1/2pi (v_sin takes revolutions)
    const float INV2PI = 0.15915494309189535f;
    float Fg = 1.0f;
    Fg = (g == 1) ? 10.079368f : Fg;
    Fg = (g == 2) ? 101.59367f : Fg;
    Fg = (g == 3) ? 1024.0f    : Fg;
    Fg *= INV2PI;

    // ---- hoisted A-fragments: afrag[mt][i] = What1[j=16mt+c][k=8g+i] ----
    // orig feature index: i<3 -> 3+6g+i (sin_g x_i); 3<=i<6 -> 6+6g+(i-3)
    // (cos_g x_{i-3}); i==6 -> g<3 ? row g (x_g) : bias row; i==7 -> 0.
    bf16x8 afrag[2];
    #pragma unroll
    for (int mt = 0; mt < 2; ++mt) {
        const int j = mt * 16 + c;
        #pragma unroll
        for (int i = 0; i < 3; ++i)
            afrag[mt][i] = (__bf16)W1[(3 + 6 * g + i) * 32 + j];
        #pragma unroll
        for (int i = 3; i < 6; ++i)
            afrag[mt][i] = (__bf16)W1[(6 + 6 * g + (i - 3)) * 32 + j];
        afrag[mt][6] = (__bf16)((g < 3) ? W1[g * 32 + j] : b1[j]);
        afrag[mt][7] = (__bf16)0.0f;
    }

    // layer-2 weights for lane's j rows: j = mt*16 + g*4 + r (C-layout)
    f32x2 w2p[2][2];
    #pragma unroll
    for (int mt = 0; mt < 2; ++mt)
        #pragma unroll
        for (int rr = 0; rr < 2; ++rr) {
            w2p[mt][rr][0] = W2[mt * 16 + g * 4 + 2 * rr + 0];
            w2p[mt][rr][1] = W2[mt * 16 + g * 4 + 2 * rr + 1];
        }
    const float bias2 = b2[0];

    const int tbase = blockIdx.x * (4 * TILES) + wave * TILES;

    // ---- prefetch tile 0's x: lane needs points 16nt+c, all 3 comps ----
    float px[4][3], nx_[4][3];
    {
        const float* xb = x + (size_t)tbase * 192;   // 64 pts * 3
        #pragma unroll
        for (int nt = 0; nt < 4; ++nt)
            #pragma unroll
            for (int cm = 0; cm < 3; ++cm)
                px[nt][cm] = xb[(16 * nt + c) * 3 + cm];
    }

    #pragma unroll
    for (int t = 0; t < TILES; ++t) {
        if (t + 1 < TILES) {   // prefetch next tile under this tile's compute
            const float* xb = x + (size_t)(tbase + t + 1) * 192;
            #pragma unroll
            for (int nt = 0; nt < 4; ++nt)
                #pragma unroll
                for (int cm = 0; cm < 3; ++cm)
                    nx_[nt][cm] = xb[(16 * nt + c) * 3 + cm];
        }

        float p[4];
        #pragma unroll
        for (int nt = 0; nt < 4; ++nt) {
            const float x0 = px[nt][0], x1 = px[nt][1], x2 = px[nt][2];

            // PE at this lane's frequency only (uniform code across wave)
            const float a0 = __builtin_amdgcn_fractf(x0 * Fg);
            const float a1 = __builtin_amdgcn_fractf(x1 * Fg);
            const float a2 = __builtin_amdgcn_fractf(x2 * Fg);
            float extra = x0;
            extra = (g == 1) ? x1 : extra;
            extra = (g == 2) ? x2 : extra;
            extra = (g == 3) ? 1.0f : extra;

            bf16x8 bf;
            bf[0] = (__bf16)__builtin_amdgcn_sinf(a0);
            bf[1] = (__bf16)__builtin_amdgcn_sinf(a1);
            bf[2] = (__bf16)__builtin_amdgcn_sinf(a2);
            bf[3] = (__bf16)__builtin_amdgcn_cosf(a0);
            bf[4] = (__bf16)__builtin_amdgcn_cosf(a1);
            bf[5] = (__bf16)__builtin_amdgcn_cosf(a2);
            bf[6] = (__bf16)extra;
            bf[7] = (__bf16)0.0f;

            // layer 1: 2 MFMAs (j 0..15 and 16..31) for 16 points
            f32x4 acc0 = {0.f, 0.f, 0.f, 0.f};
            f32x4 acc1 = {0.f, 0.f, 0.f, 0.f};
            acc0 = __builtin_amdgcn_mfma_f32_16x16x32_bf16(afrag[0], bf, acc0, 0, 0, 0);
            acc1 = __builtin_amdgcn_mfma_f32_16x16x32_bf16(afrag[1], bf, acc1, 0, 0, 0);

            // layer 2 partial over lane's 8 j's
            f32x2 ps = {0.0f, 0.0f};
            #pragma unroll
            for (int rr = 0; rr < 2; ++rr) {
                f32x2 a;
                a[0] = fmaxf(acc0[2 * rr + 0], 0.0f);
                a[1] = fmaxf(acc0[2 * rr + 1], 0.0f);
                ps = ps + a * w2p[0][rr];
                f32x2 b;
                b[0] = fmaxf(acc1[2 * rr + 0], 0.0f);
                b[1] = fmaxf(acc1[2 * rr + 1], 0.0f);
                ps = ps + b * w2p[1][rr];
            }
            p[nt] = ps[0] + ps[1];
        }

        // select-exchange butterfly: lane ends with its own point (nt = g)
        const bool hi2 = (g >= 2), odd = (g & 1);
        const float s0 = hi2 ? p[0] : p[2];
        const float s1 = hi2 ? p[1] : p[3];
        const float k0 = hi2 ? p[2] : p[0];
        const float k1 = hi2 ? p[3] : p[1];
        const float r0 = k0 + __shfl_xor(s0, 32, 64);
        const float r1 = k1 + __shfl_xor(s1, 32, 64);
        const float uk = odd ? r1 : r0;
        const float us = odd ? r0 : r1;
        const float S  = uk + __shfl_xor(us, 16, 64);

        out[(tbase + t) * 64 + lane] = fmaxf(S + bias2, 0.0f);

        #pragma unroll
        for (int nt = 0; nt < 4; ++nt)
            #pragma unroll
            for (int cm = 0; cm < 3; ++cm)
                px[nt][cm] = nx_[nt][cm];
    }
}

extern "C" void kernel_launch(void* const* d_in, const int* in_sizes, int n_in,
                              void* d_out, int out_size, void* d_ws, size_t ws_size,
                              hipStream_t stream) {
    const float* x  = (const float*)d_in[0];
    const float* W1 = (const float*)d_in[1];
    const float* b1 = (const float*)d_in[2];
    const float* W2 = (const float*)d_in[3];
    const float* b2 = (const float*)d_in[4];
    float* out = (float*)d_out;

    nerf_mfma4<<<NBLK, BLOCK, 0, stream>>>(x, W1, b1, W2, b2, out);
}